// Round 9
// baseline (163.995 us; speedup 1.0000x reference)
//
#include <hip/hip_runtime.h>

// ContextGenerator: B=32, D=NOTE_RES=64, T=4096, fp32.
// res[b,t] = sum_{L=low..min(63,up-1)} dm[b,L-1,t] * s_L[t]
// Group M (L=M+pad): s_L = P_M(pad) + sum_{k=pad}^{M-1} xC[k]*pm[k+pad].
//
// R8: occupancy attack. All prior structures plateau ~30us with VALU<20% and
// HBM<30% -> latency-bound at <=18 waves/CU. Now 512 threads / 8 slim roles
// per block; dm rows 0..30 bypass LDS (register loads by their sole consumer
// waves) -> LDS 42.8 KB -> 3 blocks x 8 waves = 24 waves/CU. launch_bounds
// (512,6) caps VGPR at 85; every role sized under that (no spill arrays).
// Staging: per-lane dwordx4 -> ds_write_b128 (R7-proven).

#define TT 4096
// LDS rows: [0..63] rep | [64..126] pm 0..62 | [127..158] dm 31..62
#define NROWS 159

// Generic group32 coarse piece: k in [K0,K0+8), pads in [PA,PB).
// ldm32[pad*64+lane] = dm row 31+pad.
template <int K0, int PA, int PB>
__device__ __forceinline__ float g32(const float* __restrict__ lrep,
                                     const float* __restrict__ lpm,
                                     const float* __restrict__ ldm32, int lane,
                                     int low, int up) {
  constexpr int PE = (PB < K0 + 8) ? PB : K0 + 8;  // pads >= K0+8 are empty
  constexpr int LO = K0 + PA;
  constexpr int HI = K0 + 7 + PE - 1;
  constexpr int N = HI - LO + 1;
  float xa[8];
#pragma unroll
  for (int i = 0; i < 8; ++i)
    xa[i] = 0.5f * (lrep[(2 * (K0 + i)) * 64 + lane] +
                    lrep[(2 * (K0 + i) + 1) * 64 + lane]);
  float pmv[N];
#pragma unroll
  for (int r = 0; r < N; ++r) pmv[r] = lpm[(LO + r) * 64 + lane];
  float res = 0.f;
#pragma unroll
  for (int pad = PA; pad < PE; ++pad) {
    const int L = 32 + pad;
    const int kk0 = (pad > K0) ? pad : K0;
    float s = 0.f;
#pragma unroll
    for (int k = kk0; k < K0 + 8; ++k)
      s = fmaf(xa[k - K0], pmv[k + pad - LO], s);
    if (L >= low && L < up) res = fmaf(ldm32[pad * 64 + lane], s, res);
  }
  return res;
}

// w5: group32 fine-prefix chain (pads 1..31).
__device__ __forceinline__ float role_pfx32(const float* __restrict__ lrep,
                                            const float* __restrict__ lpm,
                                            const float* __restrict__ ldm32,
                                            int lane, int low, int up) {
  float res = 0.f, p = 0.f;
#pragma unroll
  for (int pad = 1; pad < 32; ++pad) {
    const int j = pad - 1;
    p = fmaf(lrep[(2 * j) * 64 + lane], lpm[(2 * j) * 64 + lane],
             fmaf(lrep[(2 * j + 1) * 64 + lane], lpm[(2 * j + 1) * 64 + lane],
                  p));
    const int L = 32 + pad;
    if (L >= low && L < up) res = fmaf(ldm32[pad * 64 + lane], p, res);
  }
  return res;
}

// w6: M=16 coarse sums. dmv[pad] = dm row 15+pad (pads 0..15), from registers.
__device__ __forceinline__ float role_m16(const float* __restrict__ lrep,
                                          const float* __restrict__ lpm,
                                          const float* dmv, int lane, int low,
                                          int up) {
  float x2[16];
#pragma unroll
  for (int j = 0; j < 16; ++j)
    x2[j] = 0.25f * (lrep[(4 * j) * 64 + lane] + lrep[(4 * j + 1) * 64 + lane] +
                     lrep[(4 * j + 2) * 64 + lane] +
                     lrep[(4 * j + 3) * 64 + lane]);
  float pmv[31];
#pragma unroll
  for (int r = 0; r < 31; ++r) pmv[r] = lpm[r * 64 + lane];
  float res = 0.f;
#pragma unroll
  for (int pad = 0; pad < 16; ++pad) {
    const int L = 16 + pad;
    float s = 0.f;
#pragma unroll
    for (int k = pad; k < 16; ++k) s = fmaf(x2[k], pmv[k + pad], s);
    if (L >= low && L < up) res = fmaf(dmv[pad], s, res);
  }
  return res;
}

// w7: M=16 prefix + full M=8,4,2,1 levels. dmv[i] = dm row i (i in 0..30).
template <int M>
__device__ __forceinline__ void level_step(const float* __restrict__ lpm,
                                           const float* dmv, int lane, int low,
                                           int up, float* xf, float* xc,
                                           float& res) {
  float p = 0.f;
  float q[M];
#pragma unroll
  for (int j = 0; j < M; ++j) {
    const float a = xf[2 * j], bb = xf[2 * j + 1];
    xc[j] = 0.5f * (a + bb);
    q[j] = fmaf(a, lpm[(2 * j) * 64 + lane],
                bb * lpm[(2 * j + 1) * 64 + lane]);
  }
#pragma unroll
  for (int pad = 0; pad < M; ++pad) {
    const int L = M + pad;
    float s = p;
#pragma unroll
    for (int k = pad; k < M; ++k)
      s = fmaf(xc[k], lpm[(k + pad) * 64 + lane], s);
    if (L >= low && L < up) res = fmaf(dmv[M - 1 + pad], s, res);
    p += q[pad];
  }
}

__device__ __forceinline__ float role_tail(const float* __restrict__ lrep,
                                           const float* __restrict__ lpm,
                                           const float* dmv, int lane, int low,
                                           int up) {
  float res = 0.f;
  // M=16 prefix: P16(pad)=sum_{j<pad} q1[j]; contribution dm[15+pad]*P16.
  float P = 0.f;
#pragma unroll
  for (int pad = 1; pad < 16; ++pad) {
    const int j = pad - 1;
    const float a = 0.5f * (lrep[(4 * j) * 64 + lane] +
                            lrep[(4 * j + 1) * 64 + lane]);
    const float bb = 0.5f * (lrep[(4 * j + 2) * 64 + lane] +
                             lrep[(4 * j + 3) * 64 + lane]);
    P = fmaf(a, lpm[(2 * j) * 64 + lane],
             fmaf(bb, lpm[(2 * j + 1) * 64 + lane], P));
    const int L = 16 + pad;
    if (L >= low && L < up) res = fmaf(dmv[15 + pad], P, res);
  }
  // Levels M=8,4,2,1 from x2.
  float x2[16];
#pragma unroll
  for (int j = 0; j < 16; ++j)
    x2[j] = 0.25f * (lrep[(4 * j) * 64 + lane] + lrep[(4 * j + 1) * 64 + lane] +
                     lrep[(4 * j + 2) * 64 + lane] +
                     lrep[(4 * j + 3) * 64 + lane]);
  float x3[8], x4[4], x5[2], x6[1];
  level_step<8>(lpm, dmv, lane, low, up, x2, x3, res);
  level_step<4>(lpm, dmv, lane, low, up, x3, x4, res);
  level_step<2>(lpm, dmv, lane, low, up, x4, x5, res);
  level_step<1>(lpm, dmv, lane, low, up, x5, x6, res);
  return res;
}

__global__ __launch_bounds__(512, 6) void ContextGenerator_34875134444049_kernel(
    const float* __restrict__ rep, const float* __restrict__ dm,
    const float* __restrict__ pm, const int* __restrict__ lowp,
    const int* __restrict__ upp, float* __restrict__ out) {
  __shared__ float lds[NROWS * 64 + 8 * 64];  // 42752 B -> 3 blocks/CU
  const int tid = threadIdx.x;
  const int wid = tid >> 6;
  const int lane = tid & 63;
  const int b = blockIdx.x >> 6;          // 2048 blocks: 64 chunks per batch
  const int t0 = (blockIdx.x & 63) << 6;  // 64-t slice
  const size_t base = (size_t)b * 64 * TT + (size_t)t0;

  // --- staging: 159 rows * 16 float4-slots = 2544 slots; 5 loads/thread.
  float4 v[5];
#pragma unroll
  for (int g = 0; g < 5; ++g) {
    const int slot = tid + 512 * g;
    if (slot < NROWS * 16) {
      const int row = slot >> 4;
      const int c4 = (slot & 15) << 2;
      const float* tb = (row < 64) ? rep + base + (size_t)row * TT
                      : (row < 127) ? pm + base + (size_t)(row - 64) * TT
                                    : dm + base + (size_t)(row - 96) * TT;
      v[g] = *(const float4*)(tb + c4);
    }
  }

  // --- dm rows 0..30 direct to registers for their sole consumer waves.
  const int low = lowp[0];
  const int up = upp[0];
  const float* dmg = dm + base + lane;
  float dmv[31];
  if (wid == 6) {  // needs dm rows 15..30 -> dmv[0..15]
#pragma unroll
    for (int i = 0; i < 16; ++i) dmv[i] = dmg[(size_t)(15 + i) * TT];
  } else if (wid == 7) {  // needs dm rows 0..30 -> dmv[0..30]
#pragma unroll
    for (int i = 0; i < 31; ++i) dmv[i] = dmg[(size_t)i * TT];
  }

#pragma unroll
  for (int g = 0; g < 5; ++g) {
    const int slot = tid + 512 * g;
    if (slot < NROWS * 16) *(float4*)(&lds[slot << 2]) = v[g];
  }
  __syncthreads();

  const float* lrep = lds;
  const float* lpm = lds + 64 * 64;
  const float* ldm32 = lds + 127 * 64;  // ldm32[pad*64+lane] = dm row 31+pad
  float* part = lds + NROWS * 64;

  float res;
  if (wid == 0)
    res = g32<24, 0, 16>(lrep, lpm, ldm32, lane, low, up);
  else if (wid == 1)
    res = g32<24, 16, 32>(lrep, lpm, ldm32, lane, low, up);
  else if (wid == 2)
    res = g32<16, 0, 14>(lrep, lpm, ldm32, lane, low, up);
  else if (wid == 3)
    res = g32<16, 14, 24>(lrep, lpm, ldm32, lane, low, up) +
          g32<8, 0, 8>(lrep, lpm, ldm32, lane, low, up);
  else if (wid == 4)
    res = g32<8, 8, 16>(lrep, lpm, ldm32, lane, low, up) +
          g32<0, 0, 8>(lrep, lpm, ldm32, lane, low, up);
  else if (wid == 5)
    res = role_pfx32(lrep, lpm, ldm32, lane, low, up);
  else if (wid == 6)
    res = role_m16(lrep, lpm, dmv, lane, low, up);
  else
    res = role_tail(lrep, lpm, dmv, lane, low, up);

  if (wid > 0) part[wid * 64 + lane] = res;
  __syncthreads();
  if (wid == 0) {
    float r = res;
#pragma unroll
    for (int w = 1; w < 8; ++w) r += part[w * 64 + lane];
    out[(size_t)b * TT + t0 + lane] = r;
  }
}

extern "C" void kernel_launch(void* const* d_in, const int* in_sizes, int n_in,
                              void* d_out, int out_size, void* d_ws,
                              size_t ws_size, hipStream_t stream) {
  const float* rep = (const float*)d_in[0];
  const float* dm = (const float*)d_in[1];
  const float* pm = (const float*)d_in[2];
  const int* lowp = (const int*)d_in[3];
  const int* upp = (const int*)d_in[4];
  float* out = (float*)d_out;

  const int blocks = out_size / 64;  // 131072 / 64 = 2048
  ContextGenerator_34875134444049_kernel<<<blocks, 512, 0, stream>>>(
      rep, dm, pm, lowp, upp, out);
}

// Round 10
// 158.305 us; speedup vs baseline: 1.0359x; 1.0359x over previous
//
#include <hip/hip_runtime.h>

// ContextGenerator: B=32, D=NOTE_RES=64, T=4096, fp32.
// res[b,t] = sum_{L=low..min(63,up-1)} dm[b,L-1,t] * s_L[t]
// Group M (L=M+pad, pad in [0,M)): s_L = P_M(pad) + sum_{k=pad}^{M-1} xC[k]*pm[k+pad]
//   xC = down^l(rep col), P_M(pad) = sum_{j<pad}(fine[2j]*pm[2j]+fine[2j+1]*pm[2j+1]).
//
// R10: barrier-free latency attack. LDS-staged convoy structures all plateau
// ~38-40us (both pipes <30% busy); R0's per-thread design did 49.8us at only
// 2 waves/SIMD (grid-capped). Here: split each output column across TWO
// waves -> 2048 blocks x 128 thr = 16 waves/CU (4/SIMD, 2x R0), each wave
// ~160-190 independent per-lane loads flowing freely (no stage barriers; one
// __syncthreads at the very end to combine). launch_bounds(128,4) caps VGPR
// at 128 (R0 fit the FULL problem in 84 -> no spill risk; avoids the R6/R8/R9
// failure mode of tight caps + arrays).
//
//   WA (wave 0): group32 coarse sums        (528 FMA, 159 loads)
//   WB (wave 1): group32 prefix (streamed) + groups 16/8/4/2/1
//                                           (~400 FMA, 188 loads)

#define TT 4096

__global__ __launch_bounds__(128, 4) void ContextGenerator_34875134444049_kernel(
    const float* __restrict__ rep, const float* __restrict__ dm,
    const float* __restrict__ pm, const int* __restrict__ lowp,
    const int* __restrict__ upp, float* __restrict__ out) {
  __shared__ float part[64];
  const int wid = threadIdx.x >> 6;
  const int lane = threadIdx.x & 63;
  const int b = blockIdx.x >> 6;          // 2048 blocks: 64 chunks per batch
  const int t0 = (blockIdx.x & 63) << 6;  // 64-t slice
  const size_t base = (size_t)b * 64 * TT + (size_t)t0 + (size_t)lane;

  const float* __restrict__ repc = rep + base;
  const float* __restrict__ pmc = pm + base;
  const float* __restrict__ dmc = dm + base;
  const int low = lowp[0];
  const int up = upp[0];

  float res = 0.f;

  if (wid == 0) {
    // ---- WA: group32 coarse: for pad 0..31, s = sum_{k=pad}^{31} x1[k]*pm[k+pad]
    float pmv[63];
#pragma unroll
    for (int r = 0; r < 63; ++r) pmv[r] = pmc[(size_t)r * TT];
    float x1[32];
#pragma unroll
    for (int j = 0; j < 32; ++j)
      x1[j] = 0.5f * (repc[(size_t)(2 * j) * TT] + repc[(size_t)(2 * j + 1) * TT]);
#pragma unroll
    for (int pad = 0; pad < 32; ++pad) {
      const int L = 32 + pad;
      float s = 0.f;
#pragma unroll
      for (int k = pad; k < 32; ++k) s = fmaf(x1[k], pmv[k + pad], s);
      if (L >= low && L < up) res = fmaf(dmc[(size_t)(31 + pad) * TT], s, res);
    }
  } else {
    // ---- WB part 1: group32 fine-prefix, fully streamed (register-light).
    // P(pad) = sum_{j<pad} (rep[2j]*pm[2j] + rep[2j+1]*pm[2j+1]);
    // contribution at pad=j+1: dm[32+j] * P.
    float x1[32], pmv[32];
    float P = 0.f;
#pragma unroll
    for (int j = 0; j < 31; ++j) {
      const float a = repc[(size_t)(2 * j) * TT];
      const float c = repc[(size_t)(2 * j + 1) * TT];
      const float pa = pmc[(size_t)(2 * j) * TT];
      const float pc = pmc[(size_t)(2 * j + 1) * TT];
      x1[j] = 0.5f * (a + c);
      if (2 * j < 32) pmv[2 * j] = pa;
      if (2 * j + 1 < 32) pmv[2 * j + 1] = pc;
      P = fmaf(a, pa, fmaf(c, pc, P));
      const int L = 33 + j;
      if (L >= low && L < up) res = fmaf(dmc[(size_t)(32 + j) * TT], P, res);
    }
    x1[31] = 0.5f * (repc[(size_t)62 * TT] + repc[(size_t)63 * TT]);

    // ---- WB part 2: group16 (coarse x2 + prefix q1 from x1).
    float x2[16], q1[16];
#pragma unroll
    for (int j = 0; j < 16; ++j) {
      x2[j] = 0.5f * (x1[2 * j] + x1[2 * j + 1]);
      q1[j] = fmaf(x1[2 * j], pmv[2 * j], x1[2 * j + 1] * pmv[2 * j + 1]);
    }
    float p = 0.f;
#pragma unroll
    for (int pad = 0; pad < 16; ++pad) {
      const int L = 16 + pad;
      float s = p;
#pragma unroll
      for (int k = pad; k < 16; ++k) s = fmaf(x2[k], pmv[k + pad], s);
      if (L >= low && L < up) res = fmaf(dmc[(size_t)(15 + pad) * TT], s, res);
      p += q1[pad];
    }

    // ---- WB part 3: levels M=8,4,2,1 (coarse + prefix), dm streamed.
    float x3[8], x4[4], x5[2];
    {
      float q[8];
#pragma unroll
      for (int j = 0; j < 8; ++j) {
        x3[j] = 0.5f * (x2[2 * j] + x2[2 * j + 1]);
        q[j] = fmaf(x2[2 * j], pmv[2 * j], x2[2 * j + 1] * pmv[2 * j + 1]);
      }
      float pp = 0.f;
#pragma unroll
      for (int pad = 0; pad < 8; ++pad) {
        const int L = 8 + pad;
        float s = pp;
#pragma unroll
        for (int k = pad; k < 8; ++k) s = fmaf(x3[k], pmv[k + pad], s);
        if (L >= low && L < up) res = fmaf(dmc[(size_t)(7 + pad) * TT], s, res);
        pp += q[pad];
      }
    }
    {
      float q[4];
#pragma unroll
      for (int j = 0; j < 4; ++j) {
        x4[j] = 0.5f * (x3[2 * j] + x3[2 * j + 1]);
        q[j] = fmaf(x3[2 * j], pmv[2 * j], x3[2 * j + 1] * pmv[2 * j + 1]);
      }
      float pp = 0.f;
#pragma unroll
      for (int pad = 0; pad < 4; ++pad) {
        const int L = 4 + pad;
        float s = pp;
#pragma unroll
        for (int k = pad; k < 4; ++k) s = fmaf(x4[k], pmv[k + pad], s);
        if (L >= low && L < up) res = fmaf(dmc[(size_t)(3 + pad) * TT], s, res);
        pp += q[pad];
      }
    }
    {
      float q[2];
#pragma unroll
      for (int j = 0; j < 2; ++j) {
        x5[j] = 0.5f * (x4[2 * j] + x4[2 * j + 1]);
        q[j] = fmaf(x4[2 * j], pmv[2 * j], x4[2 * j + 1] * pmv[2 * j + 1]);
      }
      float pp = 0.f;
#pragma unroll
      for (int pad = 0; pad < 2; ++pad) {
        const int L = 2 + pad;
        float s = pp;
#pragma unroll
        for (int k = pad; k < 2; ++k) s = fmaf(x5[k], pmv[k + pad], s);
        if (L >= low && L < up) res = fmaf(dmc[(size_t)(1 + pad) * TT], s, res);
        pp += q[pad];
      }
    }
    {
      const float x6 = 0.5f * (x5[0] + x5[1]);
      if (1 >= low && 1 < up) res = fmaf(dmc[0], x6 * pmv[0], res);
    }
  }

  // ---- combine: one barrier, WA stores.
  if (wid == 1) part[lane] = res;
  __syncthreads();
  if (wid == 0) out[(size_t)b * TT + t0 + lane] = res + part[lane];
}

extern "C" void kernel_launch(void* const* d_in, const int* in_sizes, int n_in,
                              void* d_out, int out_size, void* d_ws,
                              size_t ws_size, hipStream_t stream) {
  const float* rep = (const float*)d_in[0];
  const float* dm = (const float*)d_in[1];
  const float* pm = (const float*)d_in[2];
  const int* lowp = (const int*)d_in[3];
  const int* upp = (const int*)d_in[4];
  float* out = (float*)d_out;

  const int blocks = out_size / 64;  // 131072 / 64 = 2048
  ContextGenerator_34875134444049_kernel<<<blocks, 128, 0, stream>>>(
      rep, dm, pm, lowp, upp, out);
}

// Round 11
// 135.169 us; speedup vs baseline: 1.2133x; 1.1712x over previous
//
#include <hip/hip_runtime.h>

// ContextGenerator: B=32, D=NOTE_RES=64, T=4096, fp32.
// res[b,t] = sum_{L=low..min(63,up-1)} dm[b,L-1,t] * s_L[t]
// Group M (L=M+pad, pad in [0,M)): s_L = P_M(pad) + sum_{k=pad}^{M-1} xC[k]*pm[k+pad]
//
// R11: R0's verified per-thread compute, but with ALL 190 column loads
// bulk-issued into register arrays BEFORE any use (deep MLP: hardware allows
// 63 outstanding vmem/wave; loads have zero interdependencies), then
// register-only FMAs. R0's 49.8us is explained by near-serial loads (84 VGPR
// -> ~2 outstanding); R10's regression by VGPR=56. Fix: launch_bounds(256,2)
// gives the allocator a 256-VGPR/wave budget so ~200 live floats fit WITHOUT
// spilling and WITHOUT the allocator chasing 4 waves/SIMD. Grid 512x256 =
// 8 waves/CU, all resident in one shot, zero barriers.

#define TT 4096

// One pyramid group: window lengths L = M..2M-1. dmr[pad] = dm row M-1+pad
// (register array, constant-indexed after unroll). xa = coarse level, q =
// fine-level products for the running prefix p.
template <int M>
__device__ __forceinline__ void group_accum(const float* dmr, const float* pmv,
                                            const float* xa, const float* q,
                                            int low, int up, float& res) {
  float p = 0.f;
#pragma unroll
  for (int pad = 0; pad < M; ++pad) {
    const int L = M + pad;
    float s = p;  // = sum_{w<2*pad} fine[w]*pm[w]
#pragma unroll
    for (int k = pad; k < M; ++k) s = fmaf(xa[k], pmv[k + pad], s);
    if (L >= low && L < up) res = fmaf(dmr[pad], s, res);  // uniform branch
    p += q[pad];
  }
}

// In-place downsample: level length 2M -> M in xa[0:M]; fine products q[0:M].
template <int M>
__device__ __forceinline__ void downsample(const float* pmv, float* xa,
                                           float* q) {
#pragma unroll
  for (int j = 0; j < M; ++j) {
    const float a = xa[2 * j];
    const float c = xa[2 * j + 1];
    q[j] = fmaf(a, pmv[2 * j], c * pmv[2 * j + 1]);
    xa[j] = 0.5f * (a + c);
  }
}

__global__ __launch_bounds__(256, 2) void ContextGenerator_34875134444049_kernel(
    const float* __restrict__ rep, const float* __restrict__ dm,
    const float* __restrict__ pm, const int* __restrict__ lowp,
    const int* __restrict__ upp, float* __restrict__ out) {
  const int gid = blockIdx.x * 256 + threadIdx.x;
  const int t = gid & (TT - 1);
  const int b = gid >> 12;
  const size_t base = (size_t)b * 64 * TT + (size_t)t;

  const int low = lowp[0];
  const int up = upp[0];

  const float* __restrict__ repc = rep + base;
  const float* __restrict__ pmc = pm + base;
  const float* __restrict__ dmc = dm + base;

  // ---- Phase 1: bulk-issue ALL loads (190 independent vmem ops).
  float pmv[63];
#pragma unroll
  for (int w = 0; w < 63; ++w) pmv[w] = pmc[(size_t)w * TT];
  float rv[64];
#pragma unroll
  for (int r = 0; r < 64; ++r) rv[r] = repc[(size_t)r * TT];
  float dmh[32];  // dm rows 31..62 (group32)
#pragma unroll
  for (int i = 0; i < 32; ++i) dmh[i] = dmc[(size_t)(31 + i) * TT];
  float dml[31];  // dm rows 0..30 (groups 16..1)
#pragma unroll
  for (int i = 0; i < 31; ++i) dml[i] = dmc[(size_t)i * TT];

  // ---- Phase 2: fold rep -> level-1 (xa) + fine products (q). rv dies here.
  float xa[32], q[32];
#pragma unroll
  for (int j = 0; j < 32; ++j) {
    const float a = rv[2 * j];
    const float c = rv[2 * j + 1];
    xa[j] = 0.5f * (a + c);
    q[j] = fmaf(a, pmv[2 * j], c * pmv[2 * j + 1]);
  }

  // ---- Phase 3: register-only pyramid (R0-verified logic).
  float res = 0.f;
  group_accum<32>(dmh, pmv, xa, q, low, up, res);      // L = 32..63
  downsample<16>(pmv, xa, q);
  group_accum<16>(dml + 15, pmv, xa, q, low, up, res); // L = 16..31
  downsample<8>(pmv, xa, q);
  group_accum<8>(dml + 7, pmv, xa, q, low, up, res);   // L = 8..15
  downsample<4>(pmv, xa, q);
  group_accum<4>(dml + 3, pmv, xa, q, low, up, res);   // L = 4..7
  downsample<2>(pmv, xa, q);
  group_accum<2>(dml + 1, pmv, xa, q, low, up, res);   // L = 2..3
  downsample<1>(pmv, xa, q);
  group_accum<1>(dml, pmv, xa, q, low, up, res);       // L = 1

  out[gid] = res;
}

extern "C" void kernel_launch(void* const* d_in, const int* in_sizes, int n_in,
                              void* d_out, int out_size, void* d_ws,
                              size_t ws_size, hipStream_t stream) {
  const float* rep = (const float*)d_in[0];
  const float* dm = (const float*)d_in[1];
  const float* pm = (const float*)d_in[2];
  const int* lowp = (const int*)d_in[3];
  const int* upp = (const int*)d_in[4];
  float* out = (float*)d_out;

  const int blocks = out_size / 256;  // 131072 / 256 = 512
  ContextGenerator_34875134444049_kernel<<<blocks, 256, 0, stream>>>(
      rep, dm, pm, lowp, upp, out);
}